// Round 1
// baseline (71.888 us; speedup 1.0000x reference)
//
#include <hip/hip_runtime.h>

// SimpleRNN fwd: B=16384 seqs, T=1024 steps, H=8.
// Mapping: 4 lanes per batch element; lane l of a quad owns hidden rows
// (2l, 2l+1). All h exchange is quad-internal -> DPP quad_perm (full-rate VALU).
// 65536 threads = 1024 waves = 1 wave per SIMD on all 256 CUs.

__device__ __forceinline__ float tanh_fast(float a) {
  // tanh(a) = 1 - 2/(1+e^{2a});  e^{2a} = 2^(a*2*log2(e))
  float e = __builtin_amdgcn_exp2f(a * 2.8853900817779268f);
  float r = __builtin_amdgcn_rcpf(e + 1.0f);
  return fmaf(-2.0f, r, 1.0f);
}

template <int CTRL>
__device__ __forceinline__ float dppf(float v) {
  return __int_as_float(
      __builtin_amdgcn_mov_dpp(__float_as_int(v), CTRL, 0xF, 0xF, true));
}

#define XCOMP(v, S)                                                            \
  (((S) & 3) == 0   ? (v).x                                                    \
   : ((S) & 3) == 1 ? (v).y                                                    \
   : ((S) & 3) == 2 ? (v).z                                                    \
                    : (v).w)

// One RNN timestep. S in [0,16): x value lives in quad-lane S>>2, component S&3.
#define STEP(S)                                                                \
  {                                                                            \
    float xb = dppf<(((S) >> 2) * 0x55)>(XCOMP(cur, S)); /* bcast quad lane */ \
    float q1x = dppf<0xB1>(hx), q1y = dppf<0xB1>(hy); /* quad xor 1 */         \
    float q2x = dppf<0x4E>(hx), q2y = dppf<0x4E>(hy); /* quad xor 2 */         \
    float q3x = dppf<0x1B>(hx), q3y = dppf<0x1B>(hy); /* quad xor 3 */         \
    float u0 = fmaf(xb, wih0, bias0);                                          \
    float u1 = fmaf(xb, wih1, bias1);                                          \
    float v0 = w0b0 * hy, v1 = w1b0 * hy;                                      \
    u0 = fmaf(w0a0, hx, u0);                                                   \
    u1 = fmaf(w1a0, hx, u1);                                                   \
    v0 = fmaf(w0b1, q1y, v0);                                                  \
    v1 = fmaf(w1b1, q1y, v1);                                                  \
    u0 = fmaf(w0a1, q1x, u0);                                                  \
    u1 = fmaf(w1a1, q1x, u1);                                                  \
    v0 = fmaf(w0b2, q2y, v0);                                                  \
    v1 = fmaf(w1b2, q2y, v1);                                                  \
    u0 = fmaf(w0a2, q2x, u0);                                                  \
    u1 = fmaf(w1a2, q2x, u1);                                                  \
    v0 = fmaf(w0b3, q3y, v0);                                                  \
    v1 = fmaf(w1b3, q3y, v1);                                                  \
    u0 = fmaf(w0a3, q3x, u0);                                                  \
    u1 = fmaf(w1a3, q3x, u1);                                                  \
    hx = tanh_fast(u0 + v0);                                                   \
    hy = tanh_fast(u1 + v1);                                                   \
  }

#define STEP16()                                                               \
  STEP(0) STEP(1) STEP(2) STEP(3) STEP(4) STEP(5) STEP(6) STEP(7) STEP(8)      \
  STEP(9) STEP(10) STEP(11) STEP(12) STEP(13) STEP(14) STEP(15)

__global__ __launch_bounds__(256) void rnn_fwd(
    const float* __restrict__ in, const float* __restrict__ Wih,
    const float* __restrict__ Whh, const float* __restrict__ bih,
    const float* __restrict__ bhh, const float* __restrict__ fcw,
    const float* __restrict__ fcb, float* __restrict__ out, int B, int T) {
  int g = blockIdx.x * blockDim.x + threadIdx.x;
  int b = g >> 2;
  if (b >= B) return;
  const int l = threadIdx.x & 3;  // quad lane
  const int r0 = l * 2, r1 = r0 + 1;
  // Column pairs as delivered by quad xor-k exchange: j_k = 2*(l^k)
  const int j0 = (l ^ 0) * 2, j1 = (l ^ 1) * 2, j2 = (l ^ 2) * 2,
            j3 = (l ^ 3) * 2;

  // W_hh is row-major [8][8]: W_hh[r][c] = Whh[r*8+c]
  const float w0a0 = Whh[r0 * 8 + j0], w0b0 = Whh[r0 * 8 + j0 + 1];
  const float w0a1 = Whh[r0 * 8 + j1], w0b1 = Whh[r0 * 8 + j1 + 1];
  const float w0a2 = Whh[r0 * 8 + j2], w0b2 = Whh[r0 * 8 + j2 + 1];
  const float w0a3 = Whh[r0 * 8 + j3], w0b3 = Whh[r0 * 8 + j3 + 1];
  const float w1a0 = Whh[r1 * 8 + j0], w1b0 = Whh[r1 * 8 + j0 + 1];
  const float w1a1 = Whh[r1 * 8 + j1], w1b1 = Whh[r1 * 8 + j1 + 1];
  const float w1a2 = Whh[r1 * 8 + j2], w1b2 = Whh[r1 * 8 + j2 + 1];
  const float w1a3 = Whh[r1 * 8 + j3], w1b3 = Whh[r1 * 8 + j3 + 1];

  const float wih0 = Wih[r0], wih1 = Wih[r1];
  const float bias0 = bih[r0] + bhh[r0];
  const float bias1 = bih[r1] + bhh[r1];

  // Each lane loads a float4 (4 consecutive t); the quad covers 16 steps.
  const float* __restrict__ ip = in + (size_t)b * (size_t)T + (size_t)(4 * l);
  float4 cur = *reinterpret_cast<const float4*>(ip);
  float hx = 0.0f, hy = 0.0f;

  int tb = 0;
  for (; tb + 16 < T; tb += 16) {
    float4 nxt = *reinterpret_cast<const float4*>(ip + tb + 16);
    STEP16();
    cur = nxt;
  }
  STEP16();

  // y[b] = fc_b + sum_r fc_w[r] * h[r]; quad-reduce via DPP xor.
  float p = hx * fcw[r0] + hy * fcw[r1];
  p += dppf<0xB1>(p);
  p += dppf<0x4E>(p);
  if (l == 0) out[b] = p + fcb[0];
}

extern "C" void kernel_launch(void* const* d_in, const int* in_sizes, int n_in,
                              void* d_out, int out_size, void* d_ws,
                              size_t ws_size, hipStream_t stream) {
  const float* in = (const float*)d_in[0];
  const float* Wih = (const float*)d_in[1];
  const float* Whh = (const float*)d_in[2];
  const float* bih = (const float*)d_in[3];
  const float* bhh = (const float*)d_in[4];
  const float* fcw = (const float*)d_in[5];
  const float* fcb = (const float*)d_in[6];
  float* out = (float*)d_out;

  const int B = out_size;              // 16384
  const int T = in_sizes[0] / B;       // 1024

  const int threads = 256;
  const int total = B * 4;             // 4 lanes per batch element
  const int blocks = (total + threads - 1) / threads;
  rnn_fwd<<<blocks, threads, 0, stream>>>(in, Wih, Whh, bih, bhh, fcw, fcb,
                                          out, B, T);
}